// Round 1
// baseline (186.165 us; speedup 1.0000x reference)
//
#include <hip/hip_runtime.h>

// RGCN block-decomposition, fused edge-transform + scatter-add.
// out[t, b*8+o] += w_e * sum_i blocks[r, b, i, o] * x[s, b*8+i]   for each edge e=(s,t,r,w)
//
// One wave (64 lanes) per edge: lane = output channel. blocks table (8*8*8*8
// f32 = 16KB) staged in LDS with block-stride padded to 72 floats so the
// per-i broadcast read is a 2-lanes-per-bank pattern (conflict-free).

#define DIM 64
#define NBLK 8
#define BS 8
#define NREL 8
#define LDS_BLK_STRIDE 72                    // 64 + 8 pad floats per (r,b) block
#define LDS_REL_STRIDE (NBLK * LDS_BLK_STRIDE)  // 576
#define LDS_TOTAL (NREL * LDS_REL_STRIDE)       // 4608 floats = 18 KiB

__global__ __launch_bounds__(256) void rgcn_edge_kernel(
    const float* __restrict__ x,
    const float* __restrict__ blocks,
    const float* __restrict__ ew,
    const int* __restrict__ src,
    const int* __restrict__ tgt,
    const int* __restrict__ etype,
    float* __restrict__ out,
    int num_edges)
{
    __shared__ float blk[LDS_TOTAL];
    // Cooperative LDS fill of the blocks table (4096 f32), padded layout.
    for (int l = threadIdx.x; l < NREL * NBLK * BS * BS; l += blockDim.x) {
        int r = l >> 9;
        int b = (l >> 6) & 7;
        int i = (l >> 3) & 7;
        int j = l & 7;
        blk[r * LDS_REL_STRIDE + b * LDS_BLK_STRIDE + i * BS + j] = blocks[l];
    }
    __syncthreads();

    const int lane = threadIdx.x & 63;
    const int widb = threadIdx.x >> 6;
    const int wpb  = blockDim.x >> 6;
    const int wave = blockIdx.x * wpb + widb;
    const int total_waves = gridDim.x * wpb;
    const int b  = lane >> 3;   // which 8x8 block
    const int oo = lane & 7;    // output channel within block

    for (int e = wave; e < num_edges; e += total_waves) {
        const int   s = src[e];
        const int   t = tgt[e];
        const int   r = etype[e];
        const float w = ew[e];

        // 8 input features for this lane's block: contiguous 32B, broadcast
        // across the 8 lanes of the block (HW merges identical addresses).
        const float4* xs = reinterpret_cast<const float4*>(x + (size_t)s * DIM + b * BS);
        const float4 v0 = xs[0];
        const float4 v1 = xs[1];

        const float* bb = &blk[r * LDS_REL_STRIDE + b * LDS_BLK_STRIDE + oo];
        float acc = v0.x * bb[0 * BS] + v0.y * bb[1 * BS] +
                    v0.z * bb[2 * BS] + v0.w * bb[3 * BS] +
                    v1.x * bb[4 * BS] + v1.y * bb[5 * BS] +
                    v1.z * bb[6 * BS] + v1.w * bb[7 * BS];

        atomicAdd(&out[(size_t)t * DIM + lane], w * acc);
    }
}

extern "C" void kernel_launch(void* const* d_in, const int* in_sizes, int n_in,
                              void* d_out, int out_size, void* d_ws, size_t ws_size,
                              hipStream_t stream) {
    const float* x      = (const float*)d_in[0];
    const float* blocks = (const float*)d_in[1];
    const float* ew     = (const float*)d_in[2];
    const int*   src    = (const int*)d_in[3];
    const int*   tgt    = (const int*)d_in[4];
    const int*   etype  = (const int*)d_in[5];
    float* out = (float*)d_out;

    const int num_edges = in_sizes[2];

    // Output is accumulated with atomics -> must start from zero every call.
    hipMemsetAsync(d_out, 0, (size_t)out_size * sizeof(float), stream);

    const int threads = 256;
    const int blocks_n = 2048;   // 8192 waves, ~98 edges each; LDS fill amortized
    rgcn_edge_kernel<<<blocks_n, threads, 0, stream>>>(
        x, blocks, ew, src, tgt, etype, out, num_edges);
}